// Round 5
// baseline (550.807 us; speedup 1.0000x reference)
//
#include <hip/hip_runtime.h>
#include <cstdint>
#include <cstddef>

typedef unsigned short u16;
typedef __attribute__((ext_vector_type(8))) short short8;    // 8 bf16 (4 VGPR)
typedef __attribute__((ext_vector_type(16))) float f32x16;   // 32x32 MFMA C/D
typedef __attribute__((ext_vector_type(4))) int i32x4;

constexpr int M  = 8192;
constexpr int Nn = 4096;
constexpr int K1 = 2048;
constexpr int K2 = 4096;
constexpr int K  = K1 + K2;            // 6144
constexpr int BM = 256, BN = 256;
constexpr int NKT = K / 64;            // 96 K-tiles of BK=64
constexpr float LEAK = 0.3f;

__device__ __forceinline__ u16 f2bf(float f) {
  unsigned u = __float_as_uint(f);
  u += 0x7FFFu + ((u >> 16) & 1u);     // RNE
  return (u16)(u >> 16);
}

template<int C1, int C2>
__global__ void cast_concat(const float* __restrict__ X, const float* __restrict__ S,
                            u16* __restrict__ out, int rows)
{
  constexpr int C = C1 + C2;
  const size_t total = (size_t)rows * C / 8;
  for (size_t i = blockIdx.x * (size_t)blockDim.x + threadIdx.x; i < total;
       i += (size_t)gridDim.x * blockDim.x) {
    const size_t e = i * 8;
    const int r = (int)(e / C);
    const int c = (int)(e - (size_t)r * C);
    const float* src = (c < C1) ? (X + (size_t)r * C1 + c)
                                : (S + (size_t)r * C2 + (c - C1));
    const float4* s4 = (const float4*)src;
    float4 f0 = s4[0], f1 = s4[1];
    alignas(16) u16 tmp[8];
    tmp[0] = f2bf(f0.x); tmp[1] = f2bf(f0.y); tmp[2] = f2bf(f0.z); tmp[3] = f2bf(f0.w);
    tmp[4] = f2bf(f1.x); tmp[5] = f2bf(f1.y); tmp[6] = f2bf(f1.z); tmp[7] = f2bf(f1.w);
    *(i32x4*)(out + e) = *(i32x4*)tmp;
  }
}

__device__ __forceinline__ void gload16(const u16* g, u16* l) {
  __builtin_amdgcn_global_load_lds(
      (const __attribute__((address_space(1))) void*)g,
      (__attribute__((address_space(3))) void*)l, 16, 0, 0);
}

__device__ __forceinline__ float fast_tanh(float x) {
  const float ax = __builtin_fabsf(x);
  const float e  = __builtin_amdgcn_exp2f(ax * 2.8853900817779268f); // 2*log2(e)
  const float r  = 1.0f - 2.0f * __builtin_amdgcn_rcpf(e + 1.0f);
  return __builtin_copysignf(r, x);
}

#define BAR()   __builtin_amdgcn_s_barrier()
#define LGKM0() asm volatile("s_waitcnt lgkmcnt(0)" ::: "memory")
#define LGKM4() asm volatile("s_waitcnt lgkmcnt(4)" ::: "memory")
#define LGKM8() asm volatile("s_waitcnt lgkmcnt(8)" ::: "memory")
#define VMW8()  asm volatile("s_waitcnt vmcnt(8)" ::: "memory")
#define VMW0()  asm volatile("s_waitcnt vmcnt(0)" ::: "memory")
#define SB0()   __builtin_amdgcn_sched_barrier(0)

// 256x256 tile, BK=64, 8 waves, 32x32x16 MFMA, 8-phase/2-K-tile schedule with
// round-3's PROVEN sync skeleton (one barrier/phase; frag reads one phase
// ahead into afE/afO, bfE/bfO; counted lgkm retires current operands while
// next reads drain under MFMA; VMW0 at ph2-end and ph6-end fence DMA'd tiles
// one phase before their first ds_read -- those drains wait on 3-4-phase-old
// loads, so they're latency-covered).
// K-MAJOR LDS LAYOUT (round-3/4 bank-conflict fix, no XOR guessing):
//   16B slot index S = (rb*8 + kc)*32 + r, rb = 32-row block (0..7),
//   kc = 16B k-chunk (0..7), r = row in block (0..31).
//   READ for frag (rb, ks): element offset rb*2048 + ks*512 + lane*8 --
//   lane-LINEAR 1024B per instruction -> conflict-free by construction
//   (consecutive addresses, 2 lanes/bank aliasing = free), vs round-3's
//   row-major + XOR pattern which measured 37.7M conflict cycles.
//   WRITE: DMA puts thread tid at slot tid of each 8KB (64-row) region, so
//   the global SOURCE is permuted instead: row' = (tid>>8)*32 + (tid&31),
//   chunk' = (tid>>5)&7. 32B-granular gather; every 128B row is fully
//   consumed by sibling waves (L2-absorbed), issued 3-5 phases ahead.
// Staging map unchanged: ph3 stg B(T+2)->B0, ph4 A(T+2)->A0,
//   ph7 B(T+3)->B1, ph8 A(T+3)->A1. First reads: A1@ph3(prev ph8),
//   B1@ph4(prev ph7), A0@ph7(this ph4), B0@ph8(this ph3); VMW0@ph2-end
//   fences prev ph7/ph8, VMW0@ph6-end fences this ph3/ph4. WAR: each stg's
//   target had its last reads lgkm-retired one phase earlier + barrier.
__global__ __launch_bounds__(512, 2) void gemm_fused(
    const u16* __restrict__ A,      // [M][K] bf16
    const u16* __restrict__ W,      // [N][K] bf16
    const float* __restrict__ prev, // [M][N] fp32
    float* __restrict__ out)        // [M][N] fp32
{
  __shared__ u16 lds[65536];        // 128 KiB: A0@0 A1@16384 B0@32768 B1@49152

  const int tid  = threadIdx.x;
  const int lane = tid & 63;
  const int wid  = tid >> 6;
  const int wr   = wid >> 2;        // 0..1 -> 128-row half of C
  const int wc   = wid & 3;         // 0..3 -> 64-col quarter of C

  // XCD-aware bijective swizzle (512 % 8 == 0)
  const int cpx = gridDim.x >> 3;
  const int wg  = ((int)blockIdx.x & 7) * cpx + ((int)blockIdx.x >> 3);
  const int bn  = wg & 15;          // Nn/BN = 16
  const int bm  = wg >> 4;          // M/BM  = 32

  // staging source permutation for k-major LDS (see header comment):
  // thread tid -> (row', chunk') within each 64-row x 64-col sweep
  const int sr2 = ((tid >> 8) << 5) + (tid & 31);   // 0..63
  const int kc  = (tid >> 5) & 7;
  const u16* pA = A + (size_t)(bm * BM + sr2) * K + kc * 8;
  const u16* pW = W + (size_t)(bn * BN + sr2) * K + kc * 8;
  u16* ldsw = lds + wid * 512;      // wave-uniform slot base (1024B/wave)
  const size_t rowK64  = (size_t)64  * K;
  const size_t rowK128 = (size_t)128 * K;

  auto stg = [&](const u16* g, int dst) {   // 128 rows x 64 cols -> 2 regions
    gload16(g,          ldsw + dst);
    gload16(g + rowK64, ldsw + dst + 4096);
  };

  // fragment reads: LINEAR. rb = 32-row block within 256-row buffer.
  short8 afE[2][4], afO[2][4];      // A frags: 2 mt-locals x 4 ks
  short8 bfE[4],    bfO[4];         // B frags: 4 ks
  f32x16 acc[4][2];
  #pragma unroll
  for (int mt = 0; mt < 4; ++mt)
    #pragma unroll
    for (int ng = 0; ng < 2; ++ng) acc[mt][ng] = (f32x16)0.f;

  auto dsA = [&](short8 (&Av)[2][4], int mg, int ab) {   // 8 ds_read_b128
    #pragma unroll
    for (int mtl = 0; mtl < 2; ++mtl) {
      const int rb = wr * 4 + mg * 2 + mtl;
      #pragma unroll
      for (int ks = 0; ks < 4; ++ks)
        Av[mtl][ks] = *(const short8*)(lds + ab + rb * 2048 + ks * 512 + lane * 8);
    }
  };
  auto dsB = [&](short8 (&Bv)[4], int ng, int bb) {      // 4 ds_read_b128
    const int rb = wc * 2 + ng;
    #pragma unroll
    for (int ks = 0; ks < 4; ++ks)
      Bv[ks] = *(const short8*)(lds + bb + rb * 2048 + ks * 512 + lane * 8);
  };
  auto MM = [&](short8 (&Av)[2][4], short8 (&Bv)[4], int mg, int ng) {  // 8 MFMA
    __builtin_amdgcn_s_setprio(1);
    #pragma unroll
    for (int ks = 0; ks < 4; ++ks)
      #pragma unroll
      for (int mtl = 0; mtl < 2; ++mtl)
        acc[mg * 2 + mtl][ng] = __builtin_amdgcn_mfma_f32_32x32x16_bf16(
            Av[mtl][ks], Bv[ks], acc[mg * 2 + mtl][ng], 0, 0, 0);
    __builtin_amdgcn_s_setprio(0);
  };

  // ---- prologue: B(0),A(0),B(1),A(1) full tiles (16 loads)
  stg(pW,                 32768); stg(pW + rowK128,      32768 + 8192);
  stg(pA,                 0);     stg(pA + rowK128,      8192);
  stg(pW + 64,            49152); stg(pW + 64 + rowK128, 49152 + 8192);
  stg(pA + 64,            16384); stg(pA + 64 + rowK128, 16384 + 8192);
  VMW8();                         // B(0),A(0) landed; tile1 fenced by ph2 VMW0
  BAR();
  dsA(afE, 0, 0);                 // tile0 mg0
  dsB(bfE, 0, 32768);             // tile0 ng0

  const u16* gA = pA;
  const u16* gW = pW;
  #pragma unroll 1
  for (int i = 0; i < 47; ++i) {  // tiles T=2i (buf0), T+1 (buf1); stages T+2,T+3
    // ph1
    dsB(bfO, 1, 32768);
    LGKM4(); SB0(); MM(afE, bfE, 0, 0); BAR();
    // ph2: fence prev ph7/ph8 (tile T+1) before ph3/ph4 read it
    dsA(afO, 1, 0);
    LGKM8(); SB0(); MM(afE, bfO, 0, 1); VMW0(); BAR();
    // ph3: B0 free -> stage B(T+2) full
    dsA(afE, 0, 16384);
    stg(gW + 128, 32768); stg(gW + 128 + rowK128, 32768 + 8192);
    LGKM8(); SB0(); MM(afO, bfE, 1, 0); BAR();
    // ph4: A0 free -> stage A(T+2) full
    dsB(bfE, 0, 49152);
    stg(gA + 128, 0); stg(gA + 128 + rowK128, 8192);
    SB0(); MM(afO, bfO, 1, 1); BAR();
    // ph5
    dsB(bfO, 1, 49152);
    LGKM4(); SB0(); MM(afE, bfE, 0, 0); BAR();
    // ph6: fence ph3/ph4 (tile T+2) before ph7/ph8 read it
    dsA(afO, 1, 16384);
    LGKM8(); SB0(); MM(afE, bfO, 0, 1); VMW0(); BAR();
    // ph7: B1 free -> stage B(T+3) full
    dsA(afE, 0, 0);
    stg(gW + 192, 49152); stg(gW + 192 + rowK128, 49152 + 8192);
    LGKM8(); SB0(); MM(afO, bfE, 1, 0); BAR();
    // ph8: A1 free -> stage A(T+3) full
    dsB(bfE, 0, 32768);
    stg(gA + 192, 16384); stg(gA + 192 + rowK128, 16384 + 8192);
    SB0(); MM(afO, bfO, 1, 1); BAR();
    gA += 128; gW += 128;
  }

  // ---- tail: tiles 94 (A0,B0), 95 (A1,B1); nothing left to stage.
  // VMW0 at tp2-end fences the last iteration's ph7/ph8 DMA (tile 95)
  // before tp3/tp4 read it (3+ phases old, once per kernel).
  dsB(bfO, 1, 32768);
  LGKM4(); SB0(); MM(afE, bfE, 0, 0); BAR();
  dsA(afO, 1, 0);
  LGKM8(); SB0(); MM(afE, bfO, 0, 1); VMW0(); BAR();
  dsA(afE, 0, 16384);
  LGKM8(); SB0(); MM(afO, bfE, 1, 0); BAR();
  dsB(bfE, 0, 49152);
  SB0(); MM(afO, bfO, 1, 1); BAR();
  dsB(bfO, 1, 49152);
  LGKM4(); SB0(); MM(afE, bfE, 0, 0); BAR();
  dsA(afO, 1, 16384);
  LGKM8(); SB0(); MM(afE, bfO, 0, 1); BAR();
  LGKM0(); SB0(); MM(afO, bfE, 1, 0);
  MM(afO, bfO, 1, 1);

  // ---- epilogue: 32x32 C/D: col=lane&31, row=(j&3)+8*(j>>2)+4*(lane>>5)
  const int l31 = lane & 31, l5 = lane >> 5;
  const int crow0 = bm * BM + wr * 128 + l5 * 4;
  const int ccol0 = bn * BN + wc * 64 + l31;
  #pragma unroll
  for (int mt = 0; mt < 4; ++mt)
    #pragma unroll
    for (int ng = 0; ng < 2; ++ng)
      #pragma unroll
      for (int j = 0; j < 16; ++j) {
        const int row = crow0 + mt * 32 + (j & 3) + 8 * (j >> 2);
        const size_t off = (size_t)row * Nn + ccol0 + ng * 32;
        out[off] = (1.0f - LEAK) * prev[off] + LEAK * fast_tanh(acc[mt][ng][j]);
      }
}

extern "C" void kernel_launch(void* const* d_in, const int* in_sizes, int n_in,
                              void* d_out, int out_size, void* d_ws, size_t ws_size,
                              hipStream_t stream) {
  const float* inputs = (const float*)d_in[0];  // [8192][2048]
  const float* prev   = (const float*)d_in[1];  // [8192][4096]
  const float* w_in   = (const float*)d_in[2];  // [4096][2048]
  const float* w_res  = (const float*)d_in[3];  // [4096][4096]
  float* out = (float*)d_out;                   // [8192][4096]

  u16* Acat = (u16*)d_ws;                        // [M][K] bf16
  u16* Wcat = Acat + (size_t)M * K;              // [N][K] bf16

  cast_concat<K1, K2><<<2048, 256, 0, stream>>>(inputs, prev, Acat, M);
  cast_concat<K1, K2><<<1024, 256, 0, stream>>>(w_in, w_res, Wcat, Nn);

  gemm_fused<<<(M / BM) * (Nn / BN), 512, 0, stream>>>(Acat, Wcat, prev, out);
}

// Round 6
// 449.885 us; speedup vs baseline: 1.2243x; 1.2243x over previous
//
#include <hip/hip_runtime.h>
#include <cstdint>
#include <cstddef>

typedef unsigned short u16;
typedef __attribute__((ext_vector_type(8))) short short8;    // 8 bf16 (4 VGPR)
typedef __attribute__((ext_vector_type(16))) float f32x16;   // 32x32 MFMA C/D
typedef __attribute__((ext_vector_type(4))) int i32x4;

constexpr int M  = 8192;
constexpr int Nn = 4096;
constexpr int K1 = 2048;
constexpr int K2 = 4096;
constexpr int K  = K1 + K2;            // 6144
constexpr int BM = 256, BN = 256;
constexpr int NKT = K / 64;            // 96 K-tiles of BK=64
constexpr int NBK = K / 64;            // blocks per 64-row group = 96
constexpr float LEAK = 0.3f;

__device__ __forceinline__ u16 f2bf(float f) {
  unsigned u = __float_as_uint(f);
  u += 0x7FFFu + ((u >> 16) & 1u);     // RNE
  return (u16)(u >> 16);
}

// ---- blocked cast+concat: emits 64x64 bf16 blocks in DMA-native k-major
// slot order. Block (g,t) at ((g*NBK)+t)*4096 elements; within, slot
// s = rb2*256 + kc*32 + r  <->  row rb2*32+r, col-chunk kc (8 cols).
// This matches gemm's LDS layout exactly, so the gemm DMA source is
// tid-linear (fully coalesced 1KB/wave), fixing round-5's scattered gather.
// Transpose done via an LDS tile; global reads AND writes stay coalesced.
template<int C1, int C2>
__global__ void cast_concat_blk(const float* __restrict__ X, const float* __restrict__ S,
                                u16* __restrict__ out)
{
  __shared__ u16 tile[64 * 72];        // row-major, stride 72 (16B-aligned rows)
  const int bid = blockIdx.x;
  const int t   = bid % NBK;
  const int g   = bid / NBK;
  const int tid = threadIdx.x;         // 256
  const int row = tid >> 2;            // 0..63
  const int cs  = (tid & 3) * 16;      // 0,16,32,48
  const int gcol = t * 64 + cs;        // block col base (t<32 -> X, else S)
  const int grow = g * 64 + row;
  const float* src = (gcol < C1) ? (X + (size_t)grow * C1 + gcol)
                                 : (S + (size_t)grow * C2 + (gcol - C1));
  const float4* s4 = (const float4*)src;
  u16* d = tile + row * 72 + cs;
  #pragma unroll
  for (int q = 0; q < 4; ++q) {        // 16 fp32 -> 16 bf16, coalesced read
    float4 f = s4[q];
    d[q * 4 + 0] = f2bf(f.x); d[q * 4 + 1] = f2bf(f.y);
    d[q * 4 + 2] = f2bf(f.z); d[q * 4 + 3] = f2bf(f.w);
  }
  __syncthreads();
  u16* ob = out + (size_t)bid * 4096;
  #pragma unroll
  for (int h = 0; h < 2; ++h) {        // each thread emits slots tid, tid+256
    const int s   = tid + h * 256;
    const int rb2 = s >> 8, kc = (s >> 5) & 7, r = s & 31;
    const u16* p  = tile + (rb2 * 32 + r) * 72 + kc * 8;
    *(i32x4*)(ob + s * 8) = *(const i32x4*)p;   // coalesced 16B/lane write
  }
}

__device__ __forceinline__ void gload16(const u16* g, u16* l) {
  __builtin_amdgcn_global_load_lds(
      (const __attribute__((address_space(1))) void*)g,
      (__attribute__((address_space(3))) void*)l, 16, 0, 0);
}

__device__ __forceinline__ float fast_tanh(float x) {
  const float ax = __builtin_fabsf(x);
  const float e  = __builtin_amdgcn_exp2f(ax * 2.8853900817779268f); // 2*log2(e)
  const float r  = 1.0f - 2.0f * __builtin_amdgcn_rcpf(e + 1.0f);
  return __builtin_copysignf(r, x);
}

#define BAR()   __builtin_amdgcn_s_barrier()
#define LGKM0() asm volatile("s_waitcnt lgkmcnt(0)" ::: "memory")
#define LGKM4() asm volatile("s_waitcnt lgkmcnt(4)" ::: "memory")
#define LGKM8() asm volatile("s_waitcnt lgkmcnt(8)" ::: "memory")
#define VMW8()  asm volatile("s_waitcnt vmcnt(8)" ::: "memory")
#define VMW0()  asm volatile("s_waitcnt vmcnt(0)" ::: "memory")
#define SB0()   __builtin_amdgcn_sched_barrier(0)

// 256x256 tile, BK=64, 8 waves, 32x32x16 MFMA, 8-phase/2-K-tile schedule,
// round-5's PASSED sync skeleton (one barrier/phase; frag reads one phase
// ahead; counted lgkm retires current operands while next reads drain under
// MFMA; VMW0 at ph2/ph6 fences DMA'd tiles one phase before first read,
// waiting only on 3-4-phase-old loads).
// LDS: k-major slot layout (round-5, measured 0 bank conflicts): region
// rg (64 rows) at rg*8192B; slot s = rb2*256+kc*32+r. Frag reads are
// lane-LINEAR 1024B per ds_read_b128 -> conflict-free by construction.
// DMA (round-6 fix): A/W are pre-blocked by cast_concat_blk, so the
// global source for each 64x64 block is base + tid*16B -- fully coalesced,
// sequential k-tiles contiguous. Round 5's per-lane row/chunk gather
// (32 cache lines/wave) collapsed DMA issue rate -> MfmaUtil 35%.
__global__ __launch_bounds__(512, 2) void gemm_fused(
    const u16* __restrict__ A,      // blocked [M/64][96] 64x64 k-major blocks
    const u16* __restrict__ W,      // blocked [Nn/64][96]
    const float* __restrict__ prev, // [M][N] fp32
    float* __restrict__ out)        // [M][N] fp32
{
  __shared__ u16 lds[65536];        // 128 KiB: A0@0 A1@16384 B0@32768 B1@49152

  const int tid  = threadIdx.x;
  const int lane = tid & 63;
  const int wid  = tid >> 6;
  const int wr   = wid >> 2;        // 0..1 -> 128-row half of C
  const int wc   = wid & 3;         // 0..3 -> 64-col quarter of C

  // XCD-aware bijective swizzle (512 % 8 == 0)
  const int cpx = gridDim.x >> 3;
  const int wg  = ((int)blockIdx.x & 7) * cpx + ((int)blockIdx.x >> 3);
  const int bn  = wg & 15;          // Nn/BN = 16
  const int bm  = wg >> 4;          // M/BM  = 32

  // staging: blocked layout -> per-thread source is just +tid*8 elements.
  // Row-group stride RG = 96 blocks; tile stride = 1 block = 4096 elements.
  constexpr size_t BLK = 4096;
  constexpr size_t RG  = (size_t)NBK * BLK;       // 393216
  const u16* pA = A + (size_t)(4 * bm) * RG + tid * 8;
  const u16* pW = W + (size_t)(4 * bn) * RG + tid * 8;
  u16* ldsw = lds + wid * 512;      // wave-uniform slot base (1KB/wave)

  auto stg = [&](const u16* g, int dst) {   // 2 regions = 128 rows x 64 cols
    gload16(g,      ldsw + dst);
    gload16(g + RG, ldsw + dst + 4096);
  };
  // call sites: lower half (regions 0,1) = p? + t*BLK; upper half
  // (regions 2,3) = p? + 2*RG + t*BLK, dst+8192.

  short8 afE[2][4], afO[2][4];      // A frags: 2 mt-locals x 4 ks
  short8 bfE[4],    bfO[4];         // B frags: 4 ks
  f32x16 acc[4][2];
  #pragma unroll
  for (int mt = 0; mt < 4; ++mt)
    #pragma unroll
    for (int ng = 0; ng < 2; ++ng) acc[mt][ng] = (f32x16)0.f;

  auto dsA = [&](short8 (&Av)[2][4], int mg, int ab) {   // 8 ds_read_b128
    #pragma unroll
    for (int mtl = 0; mtl < 2; ++mtl) {
      const int rb = wr * 4 + mg * 2 + mtl;
      #pragma unroll
      for (int ks = 0; ks < 4; ++ks)
        Av[mtl][ks] = *(const short8*)(lds + ab + rb * 2048 + ks * 512 + lane * 8);
    }
  };
  auto dsB = [&](short8 (&Bv)[4], int ng, int bb) {      // 4 ds_read_b128
    const int rb = wc * 2 + ng;
    #pragma unroll
    for (int ks = 0; ks < 4; ++ks)
      Bv[ks] = *(const short8*)(lds + bb + rb * 2048 + ks * 512 + lane * 8);
  };
  auto MM = [&](short8 (&Av)[2][4], short8 (&Bv)[4], int mg, int ng) {  // 8 MFMA
    __builtin_amdgcn_s_setprio(1);
    #pragma unroll
    for (int ks = 0; ks < 4; ++ks)
      #pragma unroll
      for (int mtl = 0; mtl < 2; ++mtl)
        acc[mg * 2 + mtl][ng] = __builtin_amdgcn_mfma_f32_32x32x16_bf16(
            Av[mtl][ks], Bv[ks], acc[mg * 2 + mtl][ng], 0, 0, 0);
    __builtin_amdgcn_s_setprio(0);
  };

  // ---- prologue: B(0),A(0),B(1),A(1) full tiles (16 loads)
  stg(pW,                32768); stg(pW + 2 * RG,       32768 + 8192);
  stg(pA,                0);     stg(pA + 2 * RG,       8192);
  stg(pW + BLK,          49152); stg(pW + 2 * RG + BLK, 49152 + 8192);
  stg(pA + BLK,          16384); stg(pA + 2 * RG + BLK, 16384 + 8192);
  VMW8();                         // B(0),A(0) landed; tile1 fenced by ph2 VMW0
  BAR();
  dsA(afE, 0, 0);                 // tile0 mg0
  dsB(bfE, 0, 32768);             // tile0 ng0

  const u16* gA = pA;
  const u16* gW = pW;
  #pragma unroll 1
  for (int i = 0; i < 47; ++i) {  // tiles T=2i (buf0), T+1 (buf1); stages T+2,T+3
    // ph1
    dsB(bfO, 1, 32768);
    LGKM4(); SB0(); MM(afE, bfE, 0, 0); BAR();
    // ph2: fence prev ph7/ph8 (tile T+1) before ph3/ph4 read it
    dsA(afO, 1, 0);
    LGKM8(); SB0(); MM(afE, bfO, 0, 1); VMW0(); BAR();
    // ph3: B0 free -> stage B(T+2) full
    dsA(afE, 0, 16384);
    stg(gW + 2 * BLK, 32768); stg(gW + 2 * RG + 2 * BLK, 32768 + 8192);
    LGKM8(); SB0(); MM(afO, bfE, 1, 0); BAR();
    // ph4: A0 free -> stage A(T+2) full
    dsB(bfE, 0, 49152);
    stg(gA + 2 * BLK, 0); stg(gA + 2 * RG + 2 * BLK, 8192);
    SB0(); MM(afO, bfO, 1, 1); BAR();
    // ph5
    dsB(bfO, 1, 49152);
    LGKM4(); SB0(); MM(afE, bfE, 0, 0); BAR();
    // ph6: fence ph3/ph4 (tile T+2) before ph7/ph8 read it
    dsA(afO, 1, 16384);
    LGKM8(); SB0(); MM(afE, bfO, 0, 1); VMW0(); BAR();
    // ph7: B1 free -> stage B(T+3) full
    dsA(afE, 0, 0);
    stg(gW + 3 * BLK, 49152); stg(gW + 2 * RG + 3 * BLK, 49152 + 8192);
    LGKM8(); SB0(); MM(afO, bfE, 1, 0); BAR();
    // ph8: A1 free -> stage A(T+3) full
    dsB(bfE, 0, 32768);
    stg(gA + 3 * BLK, 16384); stg(gA + 2 * RG + 3 * BLK, 16384 + 8192);
    SB0(); MM(afO, bfO, 1, 1); BAR();
    gA += 2 * BLK; gW += 2 * BLK;
  }

  // ---- tail: tiles 94 (A0,B0), 95 (A1,B1); nothing left to stage.
  // VMW0 at tp2-end fences last iteration's ph7/ph8 DMA (tile 95)
  // before tp3/tp4 read it (3+ phases old, once per kernel).
  dsB(bfO, 1, 32768);
  LGKM4(); SB0(); MM(afE, bfE, 0, 0); BAR();
  dsA(afO, 1, 0);
  LGKM8(); SB0(); MM(afE, bfO, 0, 1); VMW0(); BAR();
  dsA(afE, 0, 16384);
  LGKM8(); SB0(); MM(afO, bfE, 1, 0); BAR();
  dsB(bfE, 0, 49152);
  SB0(); MM(afO, bfO, 1, 1); BAR();
  dsB(bfO, 1, 49152);
  LGKM4(); SB0(); MM(afE, bfE, 0, 0); BAR();
  dsA(afO, 1, 16384);
  LGKM8(); SB0(); MM(afE, bfO, 0, 1); BAR();
  LGKM0(); SB0(); MM(afO, bfE, 1, 0);
  MM(afO, bfO, 1, 1);

  // ---- epilogue: 32x32 C/D: col=lane&31, row=(j&3)+8*(j>>2)+4*(lane>>5)
  const int l31 = lane & 31, l5 = lane >> 5;
  const int crow0 = bm * BM + wr * 128 + l5 * 4;
  const int ccol0 = bn * BN + wc * 64 + l31;
  #pragma unroll
  for (int mt = 0; mt < 4; ++mt)
    #pragma unroll
    for (int ng = 0; ng < 2; ++ng)
      #pragma unroll
      for (int j = 0; j < 16; ++j) {
        const int row = crow0 + mt * 32 + (j & 3) + 8 * (j >> 2);
        const size_t off = (size_t)row * Nn + ccol0 + ng * 32;
        out[off] = (1.0f - LEAK) * prev[off] + LEAK * fast_tanh(acc[mt][ng][j]);
      }
}

extern "C" void kernel_launch(void* const* d_in, const int* in_sizes, int n_in,
                              void* d_out, int out_size, void* d_ws, size_t ws_size,
                              hipStream_t stream) {
  const float* inputs = (const float*)d_in[0];  // [8192][2048]
  const float* prev   = (const float*)d_in[1];  // [8192][4096]
  const float* w_in   = (const float*)d_in[2];  // [4096][2048]
  const float* w_res  = (const float*)d_in[3];  // [4096][4096]
  float* out = (float*)d_out;                   // [8192][4096]

  u16* Acat = (u16*)d_ws;                        // blocked [M/64][96] 4096-el blocks
  u16* Wcat = Acat + (size_t)M * K;              // blocked [Nn/64][96]

  cast_concat_blk<K1, K2><<<(M / 64) * NBK, 256, 0, stream>>>(inputs, prev, Acat);
  cast_concat_blk<K1, K2><<<(Nn / 64) * NBK, 256, 0, stream>>>(w_in, w_res, Wcat);

  gemm_fused<<<(M / BM) * (Nn / BN), 512, 0, stream>>>(Acat, Wcat, prev, out);
}

// Round 8
// 445.347 us; speedup vs baseline: 1.2368x; 1.0102x over previous
//
#include <hip/hip_runtime.h>
#include <cstdint>
#include <cstddef>

typedef unsigned short u16;
typedef __attribute__((ext_vector_type(8))) short short8;    // 8 bf16 (4 VGPR)
typedef __attribute__((ext_vector_type(16))) float f32x16;   // 32x32 MFMA C/D
typedef __attribute__((ext_vector_type(4))) float f32x4;     // true vector 16B
typedef __attribute__((ext_vector_type(4))) int i32x4;

constexpr int M  = 8192;
constexpr int Nn = 4096;
constexpr int K1 = 2048;
constexpr int K2 = 4096;
constexpr int K  = K1 + K2;            // 6144
constexpr int BM = 256, BN = 256;
constexpr int NKT = K / 64;            // 96 K-tiles of BK=64
constexpr int NBK = K / 64;            // blocks per 64-row group = 96
constexpr float LEAK = 0.3f;

__device__ __forceinline__ u16 f2bf(float f) {
  unsigned u = __float_as_uint(f);
  u += 0x7FFFu + ((u >> 16) & 1u);     // RNE
  return (u16)(u >> 16);
}

// ---- blocked cast+concat: emits 64x64 bf16 blocks in DMA-native k-major
// slot order. Block (g,t) at ((g*NBK)+t)*4096 elements; within, slot
// s = rb2*256 + kc*32 + r  <->  row rb2*32+r, col-chunk kc (8 cols).
// Matches gemm's LDS layout exactly -> gemm DMA source is tid-linear.
template<int C1, int C2>
__global__ void cast_concat_blk(const float* __restrict__ X, const float* __restrict__ S,
                                u16* __restrict__ out)
{
  __shared__ u16 tile[64 * 72];        // row-major, stride 72 (16B-aligned rows)
  const int bid = blockIdx.x;
  const int t   = bid % NBK;
  const int g   = bid / NBK;
  const int tid = threadIdx.x;         // 256
  const int row = tid >> 2;            // 0..63
  const int cs  = (tid & 3) * 16;      // 0,16,32,48
  const int gcol = t * 64 + cs;        // block col base (t<32 -> X, else S)
  const int grow = g * 64 + row;
  const float* src = (gcol < C1) ? (X + (size_t)grow * C1 + gcol)
                                 : (S + (size_t)grow * C2 + (gcol - C1));
  const float4* s4 = (const float4*)src;
  u16* d = tile + row * 72 + cs;
  #pragma unroll
  for (int q = 0; q < 4; ++q) {        // 16 fp32 -> 16 bf16, coalesced read
    float4 f = s4[q];
    d[q * 4 + 0] = f2bf(f.x); d[q * 4 + 1] = f2bf(f.y);
    d[q * 4 + 2] = f2bf(f.z); d[q * 4 + 3] = f2bf(f.w);
  }
  __syncthreads();
  u16* ob = out + (size_t)bid * 4096;
  #pragma unroll
  for (int h = 0; h < 2; ++h) {        // each thread emits slots tid, tid+256
    const int s   = tid + h * 256;
    const int rb2 = s >> 8, kc = (s >> 5) & 7, r = s & 31;
    const u16* p  = tile + (rb2 * 32 + r) * 72 + kc * 8;
    *(i32x4*)(ob + s * 8) = *(const i32x4*)p;   // coalesced 16B/lane write
  }
}

__device__ __forceinline__ void gload16(const u16* g, u16* l) {
  __builtin_amdgcn_global_load_lds(
      (const __attribute__((address_space(1))) void*)g,
      (__attribute__((address_space(3))) void*)l, 16, 0, 0);
}

__device__ __forceinline__ float fast_tanh(float x) {
  const float ax = __builtin_fabsf(x);
  const float e  = __builtin_amdgcn_exp2f(ax * 2.8853900817779268f); // 2*log2(e)
  const float r  = 1.0f - 2.0f * __builtin_amdgcn_rcpf(e + 1.0f);
  return __builtin_copysignf(r, x);
}

#define BAR()   __builtin_amdgcn_s_barrier()
#define LGKM0() asm volatile("s_waitcnt lgkmcnt(0)" ::: "memory")
#define LGKM4() asm volatile("s_waitcnt lgkmcnt(4)" ::: "memory")
#define LGKM8() asm volatile("s_waitcnt lgkmcnt(8)" ::: "memory")
#define VMW8()  asm volatile("s_waitcnt vmcnt(8)" ::: "memory")
#define VMW0()  asm volatile("s_waitcnt vmcnt(0)" ::: "memory")
#define SB0()   __builtin_amdgcn_sched_barrier(0)

// 256x256 tile, BK=64, 8 waves, 32x32x16 MFMA, 8-phase/2-K-tile schedule
// (round-6 PASSED loop, byte-identical). K-major LDS slots (0 conflicts),
// blocked-DMA source (tid-linear), counted lgkm read-ahead, VMW0 fences at
// ph2/ph6 one phase before first read of each DMA'd tile.
// ROUND-8 = round-7 with the nontemporal builtin type fixed (f32x4 ext-vector
// instead of HIP_vector_type float4). Epilogue overhaul only:
// per-wave LDS transpose of acc (LDS dead after tail; one barrier; each
// wave's last ds_reads drained by its own tp7 lgkmcnt(0) before it) into a
// 64x68-float private slice, then prev/out streamed as lane-contiguous
// f32x4 (4 rows x 256B per instr, 4-deep ILP) with NON-TEMPORAL access so
// the 256MB prev/out stream stops evicting Acat/Wcat from LLC.
__global__ __launch_bounds__(512, 2) void gemm_fused(
    const u16* __restrict__ A,      // blocked [M/64][96] 64x64 k-major blocks
    const u16* __restrict__ W,      // blocked [Nn/64][96]
    const float* __restrict__ prev, // [M][N] fp32
    float* __restrict__ out)        // [M][N] fp32
{
  // loop uses 131072 B (A0@0 A1@32768 B0@65536 B1@98304 bytes);
  // epilogue uses 8 x 17408 B private slices = 139264 B
  __shared__ u16 lds[69632];

  const int tid  = threadIdx.x;
  const int lane = tid & 63;
  const int wid  = tid >> 6;
  const int wr   = wid >> 2;        // 0..1 -> 128-row half of C
  const int wc   = wid & 3;         // 0..3 -> 64-col quarter of C

  // XCD-aware bijective swizzle (512 % 8 == 0)
  const int cpx = gridDim.x >> 3;
  const int wg  = ((int)blockIdx.x & 7) * cpx + ((int)blockIdx.x >> 3);
  const int bn  = wg & 15;          // Nn/BN = 16
  const int bm  = wg >> 4;          // M/BM  = 32

  // staging: blocked layout -> per-thread source is just +tid*8 elements.
  constexpr size_t BLK = 4096;
  constexpr size_t RG  = (size_t)NBK * BLK;       // 393216
  const u16* pA = A + (size_t)(4 * bm) * RG + tid * 8;
  const u16* pW = W + (size_t)(4 * bn) * RG + tid * 8;
  u16* ldsw = lds + wid * 512;      // wave-uniform slot base (1KB/wave)

  auto stg = [&](const u16* g, int dst) {   // 2 regions = 128 rows x 64 cols
    gload16(g,      ldsw + dst);
    gload16(g + RG, ldsw + dst + 4096);
  };

  short8 afE[2][4], afO[2][4];      // A frags: 2 mt-locals x 4 ks
  short8 bfE[4],    bfO[4];         // B frags: 4 ks
  f32x16 acc[4][2];
  #pragma unroll
  for (int mt = 0; mt < 4; ++mt)
    #pragma unroll
    for (int ng = 0; ng < 2; ++ng) acc[mt][ng] = (f32x16)0.f;

  auto dsA = [&](short8 (&Av)[2][4], int mg, int ab) {   // 8 ds_read_b128
    #pragma unroll
    for (int mtl = 0; mtl < 2; ++mtl) {
      const int rb = wr * 4 + mg * 2 + mtl;
      #pragma unroll
      for (int ks = 0; ks < 4; ++ks)
        Av[mtl][ks] = *(const short8*)(lds + ab + rb * 2048 + ks * 512 + lane * 8);
    }
  };
  auto dsB = [&](short8 (&Bv)[4], int ng, int bb) {      // 4 ds_read_b128
    const int rb = wc * 2 + ng;
    #pragma unroll
    for (int ks = 0; ks < 4; ++ks)
      Bv[ks] = *(const short8*)(lds + bb + rb * 2048 + ks * 512 + lane * 8);
  };
  auto MM = [&](short8 (&Av)[2][4], short8 (&Bv)[4], int mg, int ng) {  // 8 MFMA
    __builtin_amdgcn_s_setprio(1);
    #pragma unroll
    for (int ks = 0; ks < 4; ++ks)
      #pragma unroll
      for (int mtl = 0; mtl < 2; ++mtl)
        acc[mg * 2 + mtl][ng] = __builtin_amdgcn_mfma_f32_32x32x16_bf16(
            Av[mtl][ks], Bv[ks], acc[mg * 2 + mtl][ng], 0, 0, 0);
    __builtin_amdgcn_s_setprio(0);
  };

  // ---- prologue: B(0),A(0),B(1),A(1) full tiles (16 loads)
  stg(pW,                32768); stg(pW + 2 * RG,       32768 + 8192);
  stg(pA,                0);     stg(pA + 2 * RG,       8192);
  stg(pW + BLK,          49152); stg(pW + 2 * RG + BLK, 49152 + 8192);
  stg(pA + BLK,          16384); stg(pA + 2 * RG + BLK, 16384 + 8192);
  VMW8();                         // B(0),A(0) landed; tile1 fenced by ph2 VMW0
  BAR();
  dsA(afE, 0, 0);                 // tile0 mg0
  dsB(bfE, 0, 32768);             // tile0 ng0

  const u16* gA = pA;
  const u16* gW = pW;
  #pragma unroll 1
  for (int i = 0; i < 47; ++i) {  // tiles T=2i (buf0), T+1 (buf1); stages T+2,T+3
    // ph1
    dsB(bfO, 1, 32768);
    LGKM4(); SB0(); MM(afE, bfE, 0, 0); BAR();
    // ph2: fence prev ph7/ph8 (tile T+1) before ph3/ph4 read it
    dsA(afO, 1, 0);
    LGKM8(); SB0(); MM(afE, bfO, 0, 1); VMW0(); BAR();
    // ph3: B0 free -> stage B(T+2) full
    dsA(afE, 0, 16384);
    stg(gW + 2 * BLK, 32768); stg(gW + 2 * RG + 2 * BLK, 32768 + 8192);
    LGKM8(); SB0(); MM(afO, bfE, 1, 0); BAR();
    // ph4: A0 free -> stage A(T+2) full
    dsB(bfE, 0, 49152);
    stg(gA + 2 * BLK, 0); stg(gA + 2 * RG + 2 * BLK, 8192);
    SB0(); MM(afO, bfO, 1, 1); BAR();
    // ph5
    dsB(bfO, 1, 49152);
    LGKM4(); SB0(); MM(afE, bfE, 0, 0); BAR();
    // ph6: fence ph3/ph4 (tile T+2) before ph7/ph8 read it
    dsA(afO, 1, 16384);
    LGKM8(); SB0(); MM(afE, bfO, 0, 1); VMW0(); BAR();
    // ph7: B1 free -> stage B(T+3) full
    dsA(afE, 0, 0);
    stg(gW + 3 * BLK, 49152); stg(gW + 2 * RG + 3 * BLK, 49152 + 8192);
    LGKM8(); SB0(); MM(afO, bfE, 1, 0); BAR();
    // ph8: A1 free -> stage A(T+3) full
    dsB(bfE, 0, 32768);
    stg(gA + 3 * BLK, 16384); stg(gA + 2 * RG + 3 * BLK, 16384 + 8192);
    SB0(); MM(afO, bfO, 1, 1); BAR();
    gA += 2 * BLK; gW += 2 * BLK;
  }

  // ---- tail: tiles 94 (A0,B0), 95 (A1,B1); nothing left to stage.
  dsB(bfO, 1, 32768);
  LGKM4(); SB0(); MM(afE, bfE, 0, 0); BAR();
  dsA(afO, 1, 0);
  LGKM8(); SB0(); MM(afE, bfO, 0, 1); VMW0(); BAR();
  dsA(afE, 0, 16384);
  LGKM8(); SB0(); MM(afO, bfE, 1, 0); BAR();
  dsB(bfE, 0, 49152);
  SB0(); MM(afO, bfO, 1, 1); BAR();
  dsB(bfO, 1, 49152);
  LGKM4(); SB0(); MM(afE, bfE, 0, 0); BAR();
  dsA(afO, 1, 16384);
  LGKM8(); SB0(); MM(afE, bfO, 0, 1); BAR();
  LGKM0(); SB0(); MM(afO, bfE, 1, 0);
  MM(afO, bfO, 1, 1);

  // ---- epilogue (round-7/8): per-wave LDS transpose + f32x4 nt streams.
  // Safe LDS reuse: every wave's last ds_reads (tp6) completed at its own
  // tp7 lgkmcnt(0), which precedes this barrier; slice writes start only
  // after ALL waves passed it.
  BAR();
  float* T = (float*)((char*)lds + wid * 17408);   // 64 rows x 68 floats
  const int l31 = lane & 31, l5 = lane >> 5;
  const int c16 = lane & 15, g4 = lane >> 4;
  #pragma unroll
  for (int ch = 0; ch < 2; ++ch) {
    // scatter acc quadrants for rows [ch*64, ch*64+64) into the slice.
    // banks: 32 consecutive cols x 2 row-groups (stride 68 => +16 banks)
    // -> 2 lanes/bank = free.
    #pragma unroll
    for (int mtl = 0; mtl < 2; ++mtl)
      #pragma unroll
      for (int ng = 0; ng < 2; ++ng)
        #pragma unroll
        for (int j = 0; j < 16; ++j) {
          const int rowl = mtl * 32 + (j & 3) + 8 * (j >> 2) + l5 * 4;
          T[rowl * 68 + ng * 32 + l31] = acc[ch * 2 + mtl][ng][j];
        }
    LGKM0();                       // writes retired before transposed reads
    const int grow0 = bm * BM + wr * 128 + ch * 64;
    const size_t gcb = (size_t)(bn * BN + wc * 64 + c16 * 4);
    #pragma unroll 4
    for (int q = 0; q < 16; ++q) {
      const int rowl = q * 4 + g4;
      const f32x4 t = *(const f32x4*)&T[rowl * 68 + c16 * 4];
      const size_t off = (size_t)(grow0 + rowl) * Nn + gcb;
      const f32x4 p = __builtin_nontemporal_load((const f32x4*)(prev + off));
      f32x4 o;
      o.x = (1.0f - LEAK) * p.x + LEAK * fast_tanh(t.x);
      o.y = (1.0f - LEAK) * p.y + LEAK * fast_tanh(t.y);
      o.z = (1.0f - LEAK) * p.z + LEAK * fast_tanh(t.z);
      o.w = (1.0f - LEAK) * p.w + LEAK * fast_tanh(t.w);
      __builtin_nontemporal_store(o, (f32x4*)(out + off));
    }
    // ch=1 slice writes follow this wave's own reads in program order;
    // DS ops complete in-order per wave -> no extra sync needed.
  }
}

extern "C" void kernel_launch(void* const* d_in, const int* in_sizes, int n_in,
                              void* d_out, int out_size, void* d_ws, size_t ws_size,
                              hipStream_t stream) {
  const float* inputs = (const float*)d_in[0];  // [8192][2048]
  const float* prev   = (const float*)d_in[1];  // [8192][4096]
  const float* w_in   = (const float*)d_in[2];  // [4096][2048]
  const float* w_res  = (const float*)d_in[3];  // [4096][4096]
  float* out = (float*)d_out;                   // [8192][4096]

  u16* Acat = (u16*)d_ws;                        // blocked [M/64][96] 4096-el blocks
  u16* Wcat = Acat + (size_t)M * K;              // blocked [Nn/64][96]

  cast_concat_blk<K1, K2><<<(M / 64) * NBK, 256, 0, stream>>>(inputs, prev, Acat);
  cast_concat_blk<K1, K2><<<(Nn / 64) * NBK, 256, 0, stream>>>(w_in, w_res, Wcat);

  gemm_fused<<<(M / BM) * (Nn / BN), 512, 0, stream>>>(Acat, Wcat, prev, out);
}